// Round 7
// baseline (398.215 us; speedup 1.0000x reference)
//
#include <hip/hip_runtime.h>

// FullGRUODECell_Autonomous_fine — MI355X (gfx950)
//
// dh = (1-z)*(u-h);  z = sigmoid(h@Whz^T + hz);  u = tanh((r*h)@Whh^T);
// r = sigmoid(h@Whr^T);  hz[b,i] = sum_{j,k} h[b,j] h[b,k] Wfine[i*256+j,k]
//
// hz = G @ Wf^T with G[b, j*256+k]=h[b,j]h[b,k], Wf = Wfine viewed [256][65536].
// K1 k_convert: Wf f32 -> W2t fp16 LINEAR blocked [2048 blk][256 col][32], h -> fp16.
// K2 k_gemm: 256x256 tile, 64 kc x 4 mt (XCD-colocated). kwin-outer loop:
//    A (16KB) staged once per 4 steps (dbuf), B (16KB fp16) depth-3 ring.
//    Per step = 2 phases {ds_reads; barrier; setprio + 16 MFMA; barrier},
//    end-of-step counted vmcnt (never 0 mid-loop). Swizzle: LDS slot
//    lg ^ ((row^(row>>2))&3), baked into per-lane gld SOURCE (linear dest).
// K3 k_final: gates + unrolled hz partial reduction + epilogue.

typedef _Float16 f16;
typedef _Float16 f16x8 __attribute__((ext_vector_type(8)));
typedef _Float16 f16x4 __attribute__((ext_vector_type(4)));
typedef float f32x4 __attribute__((ext_vector_type(4)));

__device__ __forceinline__ void gld_lds16(const void* gp, void* lp) {
  __builtin_amdgcn_global_load_lds(
      (const __attribute__((address_space(1))) unsigned int*)gp,
      (__attribute__((address_space(3))) unsigned int*)lp, 16, 0, 0);
}

// ---------------- K1: Wf f32 -> W2t fp16 (linear blocked) + h -> fp16
__global__ __launch_bounds__(256) void k_convert(
    const float* __restrict__ Wf, const float* __restrict__ h,
    f16* __restrict__ W2t, f16* __restrict__ hh) {
  const int gtid = blockIdx.x * 256 + threadIdx.x;
  const int w = gtid >> 6;
  const int l = gtid & 63;
  if (w < 65536) {
    const int n = w >> 8;          // output col (Wf row) 0..255
    const int c = w & 255;         // 256-wide jk chunk
    const int jk = c * 256 + l * 4;
    float4 v = *(const float4*)(Wf + ((size_t)n << 16) + jk);
    f16x4 o;
    o[0] = (f16)v.x; o[1] = (f16)v.y; o[2] = (f16)v.z; o[3] = (f16)v.w;
    // linear: W2t[blk][n][jk&31]
    const size_t out = ((size_t)(jk >> 5) << 13) + (n << 5) + (jk & 31);
    *(f16x4*)(W2t + out) = o;
  } else {
    const int hw = w - 65536;      // 0..1023
    const int idx = hw * 256 + l * 4;
    float4 v = *(const float4*)(h + idx);
    f16x4 o;
    o[0] = (f16)v.x; o[1] = (f16)v.y; o[2] = (f16)v.z; o[3] = (f16)v.w;
    *(f16x4*)(hh + idx) = o;
  }
}

// ---------------- K2: MFMA GEMM, kwin-outer, 2-phase steps, counted vmcnt
__global__ __launch_bounds__(512, 1) void k_gemm(
    const f16* __restrict__ hh, const f16* __restrict__ W2t,
    f16* __restrict__ part) {
  __shared__ __align__(16) f16 Abuf[2][8192];  // [256 rows][4 slots x 8 halfs]
  __shared__ __align__(16) f16 Bbuf[3][8192];  // [256 cols][4 slots x 8 halfs]
  const int bid = blockIdx.x;
  const int kc = (bid & 7) + ((bid >> 5) << 3);  // XCD colocate 4 mt per kc
  const int mt = (bid >> 3) & 3;
  const int tid = threadIdx.x;
  const int wid = tid >> 6;
  const int l = tid & 63;
  const int lg = l >> 4, lr = l & 15;
  const int wm = wid >> 2, wn = wid & 3;

  // hj cache: hj4[mi][jj] = h[row(mi)][kc*4+jj]  (8 x 8B global loads, L2-hot)
  f16x4 hj4[8];
  #pragma unroll
  for (int mi = 0; mi < 8; ++mi)
    hj4[mi] = *(const f16x4*)(hh + (size_t)(mt * 256 + wm * 128 + mi * 16 + lr) * 256 + kc * 4);

  // staging sources (pre-XOR swizzle on per-lane SOURCE, linear LDS dest)
  const int arow = (wid * 2) * 16 + (l >> 2);          // chunk0 row; sA(row+16)=sA(row)
  const int sA = (arow ^ (arow >> 2)) & 3;
  const f16* asrc = hh + (size_t)(mt * 256 + arow) * 256 + (((l & 3) ^ sA) << 3);
  const int bcol = (wid * 2) * 16 + (l >> 2);
  const int sB = (bcol ^ (bcol >> 2)) & 3;
  const f16* bsrc = W2t + (size_t)bcol * 32 + (((l & 3) ^ sB) << 3);

  // read offsets (halfs), constant across loop
  int aoff[8], boff[4];
  #pragma unroll
  for (int mi = 0; mi < 8; ++mi) {
    const int row = wm * 128 + mi * 16 + lr;
    aoff[mi] = row * 32 + ((lg ^ ((row ^ (row >> 2)) & 3)) << 3);
  }
  #pragma unroll
  for (int ni = 0; ni < 4; ++ni) {
    const int col = wn * 64 + ni * 16 + lr;
    boff[ni] = col * 32 + ((lg ^ ((col ^ (col >> 2)) & 3)) << 3);
  }

  f32x4 acc[8][4];
  #pragma unroll
  for (int mi = 0; mi < 8; ++mi)
    #pragma unroll
    for (int ni = 0; ni < 4; ++ni)
      acc[mi][ni] = f32x4{0.f, 0.f, 0.f, 0.f};

  auto issue_B = [&](int m) {  // step m's B block -> ring m%3
    const int blk = (kc * 4 + (m & 3)) * 8 + (m >> 2);
    const f16* g = bsrc + ((size_t)blk << 13);
    f16* d = &Bbuf[m % 3][0];
    gld_lds16(g,            d + (wid * 2 + 0) * 512);
    gld_lds16(g + 16 * 32,  d + (wid * 2 + 1) * 512);
  };
  auto issue_A = [&](int g) {  // kwin g's A window -> dbuf g&1
    const f16* s = asrc + g * 32;
    f16* d = &Abuf[g & 1][0];
    gld_lds16(s,             d + (wid * 2 + 0) * 512);
    gld_lds16(s + 16 * 256,  d + (wid * 2 + 1) * 512);
  };

  issue_A(0); issue_B(0); issue_B(1);
  asm volatile("s_waitcnt vmcnt(2)" ::: "memory");  // A0,B0 drained (B1 in flight)
  __builtin_amdgcn_s_barrier();

  for (int kwin = 0; kwin < 8; ++kwin) {
    const int ab = kwin & 1;
    #pragma unroll
    for (int jj = 0; jj < 4; ++jj) {
      const int n = kwin * 4 + jj;
      const int bb = n % 3;
      // ---- phase 0: A frags + B0/B1 reads, prefetch issues
      f16x8 afr[8];
      #pragma unroll
      for (int mi = 0; mi < 8; ++mi) {
        f16x8 av = *(const f16x8*)(&Abuf[ab][aoff[mi]]);
        afr[mi] = av * hj4[mi][jj];  // G[b, j*256+k] = h[b,k]*h[b,j]
      }
      f16x8 b0 = *(const f16x8*)(&Bbuf[bb][boff[0]]);
      f16x8 b1 = *(const f16x8*)(&Bbuf[bb][boff[1]]);
      if (n + 2 < 32) {
        issue_B(n + 2);                      // ring slot (n+2)%3: readers done at end of n-1
        if (((n + 2) & 3) == 0) issue_A((n + 2) >> 2);  // dbuf parity: last read ended step 4g-5
      }
      __builtin_amdgcn_s_barrier();
      __builtin_amdgcn_s_setprio(1);
      #pragma unroll
      for (int mi = 0; mi < 8; ++mi) {
        acc[mi][0] = __builtin_amdgcn_mfma_f32_16x16x32_f16(afr[mi], b0, acc[mi][0], 0, 0, 0);
        acc[mi][1] = __builtin_amdgcn_mfma_f32_16x16x32_f16(afr[mi], b1, acc[mi][1], 0, 0, 0);
      }
      __builtin_amdgcn_s_setprio(0);
      __builtin_amdgcn_s_barrier();
      // ---- phase 1: B2/B3 reads
      f16x8 b2 = *(const f16x8*)(&Bbuf[bb][boff[2]]);
      f16x8 b3 = *(const f16x8*)(&Bbuf[bb][boff[3]]);
      __builtin_amdgcn_s_barrier();
      __builtin_amdgcn_s_setprio(1);
      #pragma unroll
      for (int mi = 0; mi < 8; ++mi) {
        acc[mi][2] = __builtin_amdgcn_mfma_f32_16x16x32_f16(afr[mi], b2, acc[mi][2], 0, 0, 0);
        acc[mi][3] = __builtin_amdgcn_mfma_f32_16x16x32_f16(afr[mi], b3, acc[mi][3], 0, 0, 0);
      }
      __builtin_amdgcn_s_setprio(0);
      // end-of-step wait guarantees step n+1's B (and A at group starts).
      // FIFO-derived: n%4==2 -> 4 (leaves B(n+2)+A); n==30 -> 0; else 2.
      if (n < 30) {
        if ((n & 3) == 2) asm volatile("s_waitcnt vmcnt(4)" ::: "memory");
        else              asm volatile("s_waitcnt vmcnt(2)" ::: "memory");
      } else if (n == 30) {
        asm volatile("s_waitcnt vmcnt(0)" ::: "memory");
      }
      __builtin_amdgcn_s_barrier();
    }
  }

  // fp16 partial tile: part[kc][mt*256 + row][col]
  f16* pout = part + ((size_t)kc << 18) + (mt << 16);
  #pragma unroll
  for (int mi = 0; mi < 8; ++mi) {
    #pragma unroll
    for (int r = 0; r < 4; ++r) {
      const int b = wm * 128 + mi * 16 + lg * 4 + r;  // C row = (l>>4)*4 + reg
      #pragma unroll
      for (int ni = 0; ni < 4; ++ni)
        pout[(b << 8) + wn * 64 + ni * 16 + lr] = (f16)acc[mi][ni][r];  // col = l&15
    }
  }
}

// ---------------- K3: fused gates + hz reduction + epilogue
__global__ __launch_bounds__(256) void k_final(
    const float* __restrict__ h, const float* __restrict__ Whr,
    const float* __restrict__ Whz, const float* __restrict__ Whh,
    const f16* __restrict__ part, float* __restrict__ out) {
  __shared__ float hs[4][256];
  __shared__ float rhs[4][256];
  __shared__ float hzs[4][256];
  const int t = threadIdx.x;
  const int b0 = blockIdx.x << 2;  // 4 batch rows per wg
  {  // stage h
    const int row = t >> 6, col = (t & 63) << 2;
    *(float4*)(&hs[row][col]) = *(const float4*)(h + (b0 + row) * 256 + col);
  }
  {  // hz partial reduction: unrolled, 8 independent in-flight loads
    const int row = t >> 6, c4 = (t & 63) << 2;
    const f16* p = part + (b0 + row) * 256 + c4;
    float s0 = 0.f, s1 = 0.f, s2 = 0.f, s3 = 0.f;
    #pragma unroll
    for (int kb = 0; kb < 8; ++kb) {
      f16x4 v[8];
      #pragma unroll
      for (int u = 0; u < 8; ++u)
        v[u] = *(const f16x4*)(p + ((size_t)(kb * 8 + u) << 18));
      #pragma unroll
      for (int u = 0; u < 8; ++u) {
        s0 += (float)v[u][0]; s1 += (float)v[u][1];
        s2 += (float)v[u][2]; s3 += (float)v[u][3];
      }
    }
    hzs[row][c4] = s0; hzs[row][c4 + 1] = s1;
    hzs[row][c4 + 2] = s2; hzs[row][c4 + 3] = s3;
  }
  __syncthreads();
  float az[4];
  {  // r/z gates: thread t <-> output col t
    float ar[4] = {0.f, 0.f, 0.f, 0.f};
    az[0] = az[1] = az[2] = az[3] = 0.f;
    const float* wr = Whr + t * 256;
    const float* wz = Whz + t * 256;
    for (int k = 0; k < 256; k += 4) {
      float4 a = *(const float4*)(wr + k);
      float4 c = *(const float4*)(wz + k);
      #pragma unroll
      for (int q = 0; q < 4; ++q) {
        const float* hp = &hs[q][k];
        ar[q] = fmaf(a.x, hp[0], fmaf(a.y, hp[1], fmaf(a.z, hp[2], fmaf(a.w, hp[3], ar[q]))));
        az[q] = fmaf(c.x, hp[0], fmaf(c.y, hp[1], fmaf(c.z, hp[2], fmaf(c.w, hp[3], az[q]))));
      }
    }
    #pragma unroll
    for (int q = 0; q < 4; ++q) {
      const float r = 1.f / (1.f + __expf(-ar[q]));
      rhs[q][t] = r * hs[q][t];
    }
  }
  __syncthreads();
  {  // u gate + epilogue
    float au[4] = {0.f, 0.f, 0.f, 0.f};
    const float* wh = Whh + t * 256;
    for (int k = 0; k < 256; k += 4) {
      float4 a = *(const float4*)(wh + k);
      #pragma unroll
      for (int q = 0; q < 4; ++q) {
        const float* hp = &rhs[q][k];
        au[q] = fmaf(a.x, hp[0], fmaf(a.y, hp[1], fmaf(a.z, hp[2], fmaf(a.w, hp[3], au[q]))));
      }
    }
    #pragma unroll
    for (int q = 0; q < 4; ++q) {
      const float z = 1.f / (1.f + __expf(-(az[q] + hzs[q][t])));
      const float u = tanhf(au[q]);
      out[(b0 + q) * 256 + t] = (1.f - z) * (u - hs[q][t]);
    }
  }
}

extern "C" void kernel_launch(void* const* d_in, const int* in_sizes, int n_in,
                              void* d_out, int out_size, void* d_ws, size_t ws_size,
                              hipStream_t stream) {
  const float* h   = (const float*)d_in[1];
  const float* Whr = (const float*)d_in[2];
  const float* Whz = (const float*)d_in[3];
  const float* Whh = (const float*)d_in[4];
  const float* Wf  = (const float*)d_in[5];
  float* out = (float*)d_out;
  char* ws = (char*)d_ws;

  f16* hh   = (f16*)(ws);                            // 512 KiB (pad to 1 MiB)
  f16* W2t  = (f16*)(ws + (1u << 20));               // 32 MiB
  f16* part = (f16*)(ws + (1u << 20) + (1u << 25));  // 32 MiB (64 x 1024 x 256)

  k_convert<<<dim3(16640), dim3(256), 0, stream>>>(Wf, h, W2t, hh);
  k_gemm<<<dim3(256), dim3(512), 0, stream>>>(hh, W2t, part);
  k_final<<<dim3(256), dim3(256), 0, stream>>>(h, Whr, Whz, Whh, part, out);
}

// Round 8
// 193.642 us; speedup vs baseline: 2.0565x; 2.0565x over previous
//
#include <hip/hip_runtime.h>

// FullGRUODECell_Autonomous_fine — MI355X (gfx950)
//
// dh = (1-z)*(u-h);  z = sigmoid(h@Whz^T + hz);  u = tanh((r*h)@Whh^T);
// r = sigmoid(h@Whr^T);  hz[b,i] = sum_{j,k} h[b,j] h[b,k] Wfine[i*256+j,k]
//
// hz = G @ Wf^T with G[b, j*256+k]=h[b,j]h[b,k], Wf = Wfine viewed [256][65536].
// K1 k_convert: Wf f32 -> W2t fp16 blocked [2048 blk][256 col][32], with
//    bank-swizzle BAKED into the write (slot ^= (col>>1)&3); h -> hh fp16.
// K2 k_gemm: 128x128 tiles, grid 1024 = 64 kc x 8 mt x 2 nt (XCD-colocated),
//    256 thr / 4 waves, LDS 48KB -> 3 blocks/CU (m114/m97 wave-overlap).
//    SEQUENTIAL B-block streaming (round-7 jumpy order caused 658MB L2 thrash).
//    Depth-3 ring, single barrier + counted vmcnt(4)/step (round-4 skeleton).
//    A re-staged per step from hh with pre-XOR per-lane source; reads use the
//    same XOR => 2-way max bank aliasing (free per m136).
// K3 k_final: fused gates + unrolled hz partial reduction + epilogue.

typedef _Float16 f16;
typedef _Float16 f16x8 __attribute__((ext_vector_type(8)));
typedef _Float16 f16x4 __attribute__((ext_vector_type(4)));
typedef float f32x4 __attribute__((ext_vector_type(4)));

__device__ __forceinline__ void gld_lds16(const void* gp, void* lp) {
  __builtin_amdgcn_global_load_lds(
      (const __attribute__((address_space(1))) unsigned int*)gp,
      (__attribute__((address_space(3))) unsigned int*)lp, 16, 0, 0);
}

// ---------------- K1: Wf f32 -> W2t fp16 (blocked, swizzle baked) + h -> fp16
__global__ __launch_bounds__(256) void k_convert(
    const float* __restrict__ Wf, const float* __restrict__ h,
    f16* __restrict__ W2t, f16* __restrict__ hh) {
  const int gtid = blockIdx.x * 256 + threadIdx.x;
  const int w = gtid >> 6;
  const int l = gtid & 63;
  if (w < 65536) {
    const int n = w >> 8;          // output col (Wf row) 0..255
    const int c = w & 255;         // 256-wide jk chunk
    const int jk = c * 256 + l * 4;
    float4 v = *(const float4*)(Wf + ((size_t)n << 16) + jk);
    f16x4 o;
    o[0] = (f16)v.x; o[1] = (f16)v.y; o[2] = (f16)v.z; o[3] = (f16)v.w;
    const int s = (jk >> 3) & 3;   // source 16B slot within 64B row
    const int e0 = jk & 7;         // 0 or 4
    // W2t[blk][n][ (s ^ ((n>>1)&3))*8 + e0 ]
    const size_t out = ((size_t)(jk >> 5) << 13) + (n << 5) +
                       (((s ^ ((n >> 1) & 3)) << 3) | e0);
    *(f16x4*)(W2t + out) = o;
  } else {
    const int hw = w - 65536;      // 0..1023
    const int idx = hw * 256 + l * 4;
    float4 v = *(const float4*)(h + idx);
    f16x4 o;
    o[0] = (f16)v.x; o[1] = (f16)v.y; o[2] = (f16)v.z; o[3] = (f16)v.w;
    *(f16x4*)(hh + idx) = o;
  }
}

// ---------------- K2: MFMA GEMM, 128x128 tiles, 3 blocks/CU, depth-3 ring
__global__ __launch_bounds__(256, 3) void k_gemm(
    const f16* __restrict__ hh, const f16* __restrict__ W2t,
    f16* __restrict__ part) {
  __shared__ __align__(16) f16 Abuf[3][4096];  // [128 rows][4 slots x 8 halfs]
  __shared__ __align__(16) f16 Bbuf[3][4096];  // [128 cols][4 slots x 8 halfs]
  const int bid = blockIdx.x;
  // bid = (kc&7) + 8*(mt + 8*(nt + 2*(kc>>3))): colocates each kc's 16 wgs on one XCD
  const int kc = (bid & 7) + ((bid >> 7) << 3);
  const int mt = (bid >> 3) & 7;
  const int nt = (bid >> 6) & 1;
  const int tid = threadIdx.x;
  const int wid = tid >> 6;        // 0..3
  const int l = tid & 63;
  const int lg = l >> 4, lr = l & 15;
  const int wm = wid >> 1, wn = wid & 1;

  // hj4[mi] = h[row(mi)][kc*4 .. +4]  (in registers; L2-hot 8B loads)
  f16x4 hj4[4];
  #pragma unroll
  for (int mi = 0; mi < 4; ++mi)
    hj4[mi] = *(const f16x4*)(hh +
        (size_t)(mt * 128 + wm * 64 + mi * 16 + lr) * 256 + kc * 4);

  // A staging source (pre-XOR slot swizzle on per-lane SOURCE; LDS dest linear):
  // lane covers row = wid*32 + (l>>2) (+16 for chunk 1), slot q = l&3.
  const int ar0 = wid * 32 + (l >> 2);
  const f16* asrc = hh + (size_t)(mt * 128 + ar0) * 256 +
                    (((l & 3) ^ ((ar0 >> 1) & 3)) << 3);
  // ((ar0+16)>>1)&3 == (ar0>>1)&3, so chunk 1 = asrc + 16*256.
  // B staging source (swizzle baked in W2t by k_convert -> linear source):
  const int bc0 = wid * 32 + (l >> 2);          // local col
  const f16* bsrc = W2t + (size_t)(nt * 128 + bc0) * 32 + ((l & 3) << 3);

  // ds_read offsets (halfs), same XOR as the bake
  int aoff[4], boff[4];
  #pragma unroll
  for (int mi = 0; mi < 4; ++mi) {
    const int row = wm * 64 + mi * 16 + lr;
    aoff[mi] = row * 32 + ((lg ^ ((row >> 1) & 3)) << 3);
  }
  #pragma unroll
  for (int ni = 0; ni < 4; ++ni) {
    const int col = wn * 64 + ni * 16 + lr;     // local col; (global>>1)&3 same
    boff[ni] = col * 32 + ((lg ^ ((col >> 1) & 3)) << 3);
  }

  f32x4 acc[4][4];
  #pragma unroll
  for (int mi = 0; mi < 4; ++mi)
    #pragma unroll
    for (int ni = 0; ni < 4; ++ni)
      acc[mi][ni] = f32x4{0.f, 0.f, 0.f, 0.f};

  auto issue = [&](int n, int slot) {          // 4 ops/wave: 2 A + 2 B
    const f16* as = asrc + (n & 7) * 32;       // A k-window cycles mod 8
    gld_lds16(as,             &Abuf[slot][wid * 1024]);
    gld_lds16(as + 16 * 256,  &Abuf[slot][wid * 1024 + 512]);
    const f16* bs = bsrc + ((size_t)(kc * 32 + n) << 13);  // SEQUENTIAL blocks
    gld_lds16(bs,             &Bbuf[slot][wid * 1024]);
    gld_lds16(bs + 16 * 32,   &Bbuf[slot][wid * 1024 + 512]);
  };
  issue(0, 0);
  issue(1, 1);

  #pragma unroll
  for (int jj = 0; jj < 4; ++jj) {
    const f16 hjf0 = hj4[0][jj], hjf1 = hj4[1][jj];
    const f16 hjf2 = hj4[2][jj], hjf3 = hj4[3][jj];
    #pragma unroll
    for (int n8 = 0; n8 < 8; ++n8) {
      const int n = jj * 8 + n8;
      // step n's 4 ops done; step n+1's 4 stay in flight (never drain mid-loop)
      if (n < 31) asm volatile("s_waitcnt vmcnt(4)" ::: "memory");
      else        asm volatile("s_waitcnt vmcnt(0)" ::: "memory");
      __builtin_amdgcn_s_barrier();
      if (n + 2 < 32) issue(n + 2, (n + 2) % 3);  // slot (n-1)%3: readers done
      const int buf = n % 3;
      f16x8 afr[4], bfr[4];
      #pragma unroll
      for (int mi = 0; mi < 4; ++mi) {
        f16x8 av = *(const f16x8*)(&Abuf[buf][aoff[mi]]);
        const f16 hj = (mi == 0) ? hjf0 : (mi == 1) ? hjf1 : (mi == 2) ? hjf2 : hjf3;
        afr[mi] = av * hj;              // G[b, j*256+k] = h[b,k]*h[b,j]
      }
      #pragma unroll
      for (int ni = 0; ni < 4; ++ni)
        bfr[ni] = *(const f16x8*)(&Bbuf[buf][boff[ni]]);
      __builtin_amdgcn_s_setprio(1);
      #pragma unroll
      for (int mi = 0; mi < 4; ++mi)
        #pragma unroll
        for (int ni = 0; ni < 4; ++ni)
          acc[mi][ni] = __builtin_amdgcn_mfma_f32_16x16x32_f16(
              afr[mi], bfr[ni], acc[mi][ni], 0, 0, 0);
      __builtin_amdgcn_s_setprio(0);
    }
  }

  // fp16 partial tile: part[kc][mt*128 + row][nt*128 + col]
  f16* pout = part + ((size_t)kc << 18) + (mt << 15) + (nt << 7);
  #pragma unroll
  for (int mi = 0; mi < 4; ++mi) {
    #pragma unroll
    for (int r = 0; r < 4; ++r) {
      const int b = wm * 64 + mi * 16 + lg * 4 + r;   // C row = (l>>4)*4 + reg
      #pragma unroll
      for (int ni = 0; ni < 4; ++ni)
        pout[(b << 8) + wn * 64 + ni * 16 + lr] = (f16)acc[mi][ni][r];  // col = l&15
    }
  }
}

// ---------------- K3: fused gates + hz reduction + epilogue
__global__ __launch_bounds__(256) void k_final(
    const float* __restrict__ h, const float* __restrict__ Whr,
    const float* __restrict__ Whz, const float* __restrict__ Whh,
    const f16* __restrict__ part, float* __restrict__ out) {
  __shared__ float hs[4][256];
  __shared__ float rhs[4][256];
  __shared__ float hzs[4][256];
  const int t = threadIdx.x;
  const int b0 = blockIdx.x << 2;  // 4 batch rows per wg
  {  // stage h
    const int row = t >> 6, col = (t & 63) << 2;
    *(float4*)(&hs[row][col]) = *(const float4*)(h + (b0 + row) * 256 + col);
  }
  {  // hz partial reduction: unrolled, 8 independent in-flight loads
    const int row = t >> 6, c4 = (t & 63) << 2;
    const f16* p = part + (b0 + row) * 256 + c4;
    float s0 = 0.f, s1 = 0.f, s2 = 0.f, s3 = 0.f;
    #pragma unroll
    for (int kb = 0; kb < 8; ++kb) {
      f16x4 v[8];
      #pragma unroll
      for (int u = 0; u < 8; ++u)
        v[u] = *(const f16x4*)(p + ((size_t)(kb * 8 + u) << 18));
      #pragma unroll
      for (int u = 0; u < 8; ++u) {
        s0 += (float)v[u][0]; s1 += (float)v[u][1];
        s2 += (float)v[u][2]; s3 += (float)v[u][3];
      }
    }
    hzs[row][c4] = s0; hzs[row][c4 + 1] = s1;
    hzs[row][c4 + 2] = s2; hzs[row][c4 + 3] = s3;
  }
  __syncthreads();
  float az[4];
  {  // r/z gates: thread t <-> output col t
    float ar[4] = {0.f, 0.f, 0.f, 0.f};
    az[0] = az[1] = az[2] = az[3] = 0.f;
    const float* wr = Whr + t * 256;
    const float* wz = Whz + t * 256;
    for (int k = 0; k < 256; k += 4) {
      float4 a = *(const float4*)(wr + k);
      float4 c = *(const float4*)(wz + k);
      #pragma unroll
      for (int q = 0; q < 4; ++q) {
        const float* hp = &hs[q][k];
        ar[q] = fmaf(a.x, hp[0], fmaf(a.y, hp[1], fmaf(a.z, hp[2], fmaf(a.w, hp[3], ar[q]))));
        az[q] = fmaf(c.x, hp[0], fmaf(c.y, hp[1], fmaf(c.z, hp[2], fmaf(c.w, hp[3], az[q]))));
      }
    }
    #pragma unroll
    for (int q = 0; q < 4; ++q) {
      const float r = 1.f / (1.f + __expf(-ar[q]));
      rhs[q][t] = r * hs[q][t];
    }
  }
  __syncthreads();
  {  // u gate + epilogue
    float au[4] = {0.f, 0.f, 0.f, 0.f};
    const float* wh = Whh + t * 256;
    for (int k = 0; k < 256; k += 4) {
      float4 a = *(const float4*)(wh + k);
      #pragma unroll
      for (int q = 0; q < 4; ++q) {
        const float* hp = &rhs[q][k];
        au[q] = fmaf(a.x, hp[0], fmaf(a.y, hp[1], fmaf(a.z, hp[2], fmaf(a.w, hp[3], au[q]))));
      }
    }
    #pragma unroll
    for (int q = 0; q < 4; ++q) {
      const float z = 1.f / (1.f + __expf(-(az[q] + hzs[q][t])));
      const float u = tanhf(au[q]);
      out[(b0 + q) * 256 + t] = (1.f - z) * (u - hs[q][t]);
    }
  }
}

extern "C" void kernel_launch(void* const* d_in, const int* in_sizes, int n_in,
                              void* d_out, int out_size, void* d_ws, size_t ws_size,
                              hipStream_t stream) {
  const float* h   = (const float*)d_in[1];
  const float* Whr = (const float*)d_in[2];
  const float* Whz = (const float*)d_in[3];
  const float* Whh = (const float*)d_in[4];
  const float* Wf  = (const float*)d_in[5];
  float* out = (float*)d_out;
  char* ws = (char*)d_ws;

  f16* hh   = (f16*)(ws);                            // 512 KiB (pad to 1 MiB)
  f16* W2t  = (f16*)(ws + (1u << 20));               // 32 MiB
  f16* part = (f16*)(ws + (1u << 20) + (1u << 25));  // 32 MiB (64 x 1024 x 256)

  k_convert<<<dim3(16640), dim3(256), 0, stream>>>(Wf, h, W2t, hh);
  k_gemm<<<dim3(1024), dim3(256), 0, stream>>>(hh, W2t, part);
  k_final<<<dim3(256), dim3(256), 0, stream>>>(h, Whr, Whz, Whh, part, out);
}